// Round 2
// baseline (1702.342 us; speedup 1.0000x reference)
//
#include <hip/hip_runtime.h>

#define N_NODES 100000
#define N_EDGES 3200000
#define F_IN 64
#define F_OUT 128

#define BKT_SHIFT 6
#define BKT_NODES 64                                   // 1 << BKT_SHIFT
#define N_BKT ((N_NODES + BKT_NODES - 1) / BKT_NODES)  // 1563

// ---------------- Phase 1: per-bucket edge histogram ----------------
__global__ __launch_bounds__(256) void k_hist(const int* __restrict__ ei,
                                              unsigned* __restrict__ hist) {
    __shared__ unsigned lh[N_BKT];
    for (int i = threadIdx.x; i < N_BKT; i += 256) lh[i] = 0u;
    __syncthreads();
    int tid = blockIdx.x * 256 + threadIdx.x;
    int stride = gridDim.x * 256;
    for (int e = tid; e < N_EDGES; e += stride) {
        int dst = ei[e];
        atomicAdd(&lh[dst >> BKT_SHIFT], 1u);
    }
    __syncthreads();
    for (int i = threadIdx.x; i < N_BKT; i += 256) {
        unsigned v = lh[i];
        if (v) atomicAdd(&hist[i], v);
    }
}

// ---------------- Phase 2: exclusive scan over buckets ----------------
// Single block, 256 threads, 8 bins/thread (2048 >= N_BKT).
__global__ __launch_bounds__(256) void k_scan(const unsigned* __restrict__ hist,
                                              unsigned* __restrict__ base,
                                              unsigned* __restrict__ cursor) {
    __shared__ unsigned cnt[2048];
    __shared__ unsigned csum[256];
    const int t = threadIdx.x;
    for (int i = t; i < 2048; i += 256) cnt[i] = (i < N_BKT) ? hist[i] : 0u;
    __syncthreads();
    unsigned s = 0, loc[8];
    #pragma unroll
    for (int j = 0; j < 8; ++j) { loc[j] = s; s += cnt[t * 8 + j]; }
    csum[t] = s;
    __syncthreads();
    for (int off = 1; off < 256; off <<= 1) {
        unsigned v = 0;
        if (t >= off) v = csum[t - off];
        __syncthreads();
        if (t >= off) csum[t] += v;
        __syncthreads();
    }
    unsigned chunk_base = (t == 0) ? 0u : csum[t - 1];
    #pragma unroll
    for (int j = 0; j < 8; ++j) {
        int idx = t * 8 + j;
        unsigned v = chunk_base + loc[j];
        if (idx < N_BKT) { base[idx] = v; cursor[idx] = v; }
        else if (idx == N_BKT) base[idx] = v;   // == N_EDGES
    }
}

// ---------------- Phase 3: scatter packed edge records into buckets ----------------
// record.x = src | (dstLocal << 17)   (src < 2^17, dstLocal < 64)
// record.y = bits(edge_weight)
__global__ __launch_bounds__(256) void k_scatter_recs(const int* __restrict__ ei,
                                                      const float* __restrict__ ew,
                                                      unsigned* __restrict__ cursor,
                                                      uint2* __restrict__ recs) {
    int tid = blockIdx.x * 256 + threadIdx.x;
    int stride = gridDim.x * 256;
    for (int e = tid; e < N_EDGES; e += stride) {
        int dst = ei[e];
        int src = ei[N_EDGES + e];
        float w = ew[e];
        unsigned slot = atomicAdd(&cursor[dst >> BKT_SHIFT], 1u);
        recs[slot] = make_uint2((unsigned)src | ((unsigned)(dst & (BKT_NODES - 1)) << 17),
                                __float_as_uint(w));
    }
}

// ---------------- Phase 4: per-bucket LDS accumulate + fused proj/bias/ReLU ----------------
__global__ __launch_bounds__(256) void k_aggregate(const float* __restrict__ X,
                                                   const uint2* __restrict__ recs,
                                                   const unsigned* __restrict__ base,
                                                   const float* __restrict__ W,
                                                   const float* __restrict__ bias,
                                                   float* __restrict__ out) {
    __shared__ float tile[BKT_NODES * F_IN];   // 16 KB
    const int b = blockIdx.x;
    const int t = threadIdx.x;
    const int lane = t & 63;
    const int wv = t >> 6;                     // wave id 0..3

    for (int i = t; i < BKT_NODES * F_IN / 4; i += 256)
        ((float4*)tile)[i] = float4{0.f, 0.f, 0.f, 0.f};

    const int i0 = (int)base[b], i1 = (int)base[b + 1];
    __syncthreads();

    // lane = input feature; whole wave handles one edge; 4 waves + 4x unroll for MLP
    int i = i0 + wv;
    for (; i + 12 < i1; i += 16) {
        uint2 r0 = recs[i];
        uint2 r1 = recs[i + 4];
        uint2 r2 = recs[i + 8];
        uint2 r3 = recs[i + 12];
        float v0 = X[(r0.x & 0x1FFFF) * F_IN + lane] * __uint_as_float(r0.y);
        float v1 = X[(r1.x & 0x1FFFF) * F_IN + lane] * __uint_as_float(r1.y);
        float v2 = X[(r2.x & 0x1FFFF) * F_IN + lane] * __uint_as_float(r2.y);
        float v3 = X[(r3.x & 0x1FFFF) * F_IN + lane] * __uint_as_float(r3.y);
        atomicAdd(&tile[(r0.x >> 17) * F_IN + lane], v0);
        atomicAdd(&tile[(r1.x >> 17) * F_IN + lane], v1);
        atomicAdd(&tile[(r2.x >> 17) * F_IN + lane], v2);
        atomicAdd(&tile[(r3.x >> 17) * F_IN + lane], v3);
    }
    for (; i < i1; i += 4) {
        uint2 r = recs[i];
        float v = X[(r.x & 0x1FFFF) * F_IN + lane] * __uint_as_float(r.y);
        atomicAdd(&tile[(r.x >> 17) * F_IN + lane], v);
    }
    __syncthreads();

    // Fused projection: out[node, :] = ReLU(tile[node, :] @ W + bias)
    // thread -> output feature f = t & 127; group g = t >> 7 handles 32 nodes.
    // All lanes of a wave share the same node -> tile reads are LDS broadcasts.
    const int f = t & 127;
    const int g = t >> 7;
    float wcol[F_IN];
    #pragma unroll
    for (int k = 0; k < F_IN; ++k) wcol[k] = W[k * F_OUT + f];
    const float bf = bias[f];
    const int node0 = b * BKT_NODES;
    const int nbeg = g * (BKT_NODES / 2), nend = (g + 1) * (BKT_NODES / 2);
    for (int n = nbeg; n < nend; ++n) {
        int node = node0 + n;
        if (node >= N_NODES) break;
        float acc = bf;
        #pragma unroll
        for (int k4 = 0; k4 < F_IN / 4; ++k4) {
            float4 tv = *(const float4*)&tile[n * F_IN + k4 * 4];
            acc = fmaf(tv.x, wcol[k4 * 4 + 0], acc);
            acc = fmaf(tv.y, wcol[k4 * 4 + 1], acc);
            acc = fmaf(tv.z, wcol[k4 * 4 + 2], acc);
            acc = fmaf(tv.w, wcol[k4 * 4 + 3], acc);
        }
        out[(size_t)node * F_OUT + f] = fmaxf(acc, 0.0f);
    }
}

// ---------------- Fallback (round-1 path) if workspace too small ----------------
__global__ __launch_bounds__(256) void gcn_scatter_fb(const float* __restrict__ X,
                                                      const int* __restrict__ ei,
                                                      const float* __restrict__ ew,
                                                      float* __restrict__ A) {
    const int lane = threadIdx.x & 63;
    const int wave = (blockIdx.x * blockDim.x + threadIdx.x) >> 6;
    const int nW = (gridDim.x * blockDim.x) >> 6;
    for (int e = wave; e < N_EDGES; e += nW) {
        const int dst = ei[e];
        const int src = ei[N_EDGES + e];
        const float w = ew[e];
        atomicAdd(&A[dst * F_IN + lane], X[src * F_IN + lane] * w);
    }
}
__global__ __launch_bounds__(128) void gcn_proj_fb(const float* __restrict__ A,
                                                   const float* __restrict__ W,
                                                   const float* __restrict__ bias,
                                                   float* __restrict__ out) {
    __shared__ float arow[F_IN];
    const int n = blockIdx.x, f = threadIdx.x;
    if (f < F_IN) arow[f] = A[n * F_IN + f];
    __syncthreads();
    float acc = bias[f];
    #pragma unroll
    for (int k = 0; k < F_IN; ++k) acc = fmaf(arow[k], W[k * F_OUT + f], acc);
    out[n * F_OUT + f] = fmaxf(acc, 0.0f);
}

extern "C" void kernel_launch(void* const* d_in, const int* in_sizes, int n_in,
                              void* d_out, int out_size, void* d_ws, size_t ws_size,
                              hipStream_t stream) {
    const float* X    = (const float*)d_in[0];
    const int*   ei   = (const int*)  d_in[1];
    const float* ew   = (const float*)d_in[2];
    const float* W    = (const float*)d_in[3];
    const float* bias = (const float*)d_in[4];
    float*       out  = (float*)d_out;

    const size_t recs_bytes = (size_t)N_EDGES * sizeof(uint2);          // 25.6 MB
    const size_t meta_bytes = (size_t)(N_BKT + (N_BKT + 1) + N_BKT) * 4;
    if (ws_size >= recs_bytes + meta_bytes) {
        uint2*    recs   = (uint2*)d_ws;
        unsigned* hist   = (unsigned*)((char*)d_ws + recs_bytes);
        unsigned* base   = hist + N_BKT;
        unsigned* cursor = base + N_BKT + 1;

        hipMemsetAsync(hist, 0, (size_t)N_BKT * 4, stream);
        k_hist<<<512, 256, 0, stream>>>(ei, hist);
        k_scan<<<1, 256, 0, stream>>>(hist, base, cursor);
        k_scatter_recs<<<512, 256, 0, stream>>>(ei, ew, cursor, recs);
        k_aggregate<<<N_BKT, 256, 0, stream>>>(X, recs, base, W, bias, out);
    } else {
        float* A = (float*)d_ws;
        hipMemsetAsync(A, 0, (size_t)N_NODES * F_IN * sizeof(float), stream);
        gcn_scatter_fb<<<4096, 256, 0, stream>>>(X, ei, ew, A);
        gcn_proj_fb<<<N_NODES, 128, 0, stream>>>(A, W, bias, out);
    }
}

// Round 3
// 552.045 us; speedup vs baseline: 3.0837x; 3.0837x over previous
//
#include <hip/hip_runtime.h>

#define N_NODES 100000
#define N_EDGES 3200000
#define F_IN 64
#define F_OUT 128

#define SCAN_BLK 1024
#define NB_SCAN ((N_NODES + SCAN_BLK - 1) / SCAN_BLK)   // 98

// ---------------- Phase 1: per-node degree histogram ----------------
__global__ __launch_bounds__(256) void k_hist(const int* __restrict__ ei,
                                              unsigned* __restrict__ deg) {
    int tid = blockIdx.x * 256 + threadIdx.x;
    int stride = gridDim.x * 256;
    for (int e = tid; e < N_EDGES; e += stride)
        atomicAdd(&deg[ei[e]], 1u);
}

// ---------------- Phase 2: exclusive scan over 100K degrees ----------------
__global__ __launch_bounds__(SCAN_BLK) void k_scanA(const unsigned* __restrict__ deg,
                                                    unsigned* __restrict__ base,
                                                    unsigned* __restrict__ csum) {
    __shared__ unsigned s[SCAN_BLK];
    const int t = threadIdx.x;
    const int idx = blockIdx.x * SCAN_BLK + t;
    unsigned v = (idx < N_NODES) ? deg[idx] : 0u;
    s[t] = v;
    __syncthreads();
    for (int off = 1; off < SCAN_BLK; off <<= 1) {
        unsigned u = (t >= off) ? s[t - off] : 0u;
        __syncthreads();
        s[t] += u;
        __syncthreads();
    }
    if (idx < N_NODES) base[idx] = s[t] - v;          // exclusive within chunk
    if (t == SCAN_BLK - 1) csum[blockIdx.x] = s[t];   // chunk total
}

__global__ __launch_bounds__(128) void k_scanB(unsigned* __restrict__ csum,
                                               unsigned* __restrict__ base) {
    __shared__ unsigned s[128];
    const int t = threadIdx.x;
    unsigned v = (t < NB_SCAN) ? csum[t] : 0u;
    s[t] = v;
    __syncthreads();
    for (int off = 1; off < 128; off <<= 1) {
        unsigned u = (t >= off) ? s[t - off] : 0u;
        __syncthreads();
        s[t] += u;
        __syncthreads();
    }
    if (t < NB_SCAN) csum[t] = s[t] - v;              // exclusive chunk offsets
    if (t == 0) base[N_NODES] = N_EDGES;
}

__global__ __launch_bounds__(SCAN_BLK) void k_scanC(const unsigned* __restrict__ csum,
                                                    unsigned* __restrict__ base,
                                                    unsigned* __restrict__ cursor) {
    const int idx = blockIdx.x * SCAN_BLK + threadIdx.x;
    if (idx < N_NODES) {
        unsigned b = base[idx] + csum[blockIdx.x];
        base[idx] = b;
        cursor[idx] = b;
    }
}

// ---------------- Phase 3: scatter {src, w} records, grouped by dst ----------------
__global__ __launch_bounds__(256) void k_scatter(const int* __restrict__ ei,
                                                 const float* __restrict__ ew,
                                                 unsigned* __restrict__ cursor,
                                                 uint2* __restrict__ recs) {
    int tid = blockIdx.x * 256 + threadIdx.x;
    int stride = gridDim.x * 256;
    for (int e = tid; e < N_EDGES; e += stride) {
        int dst = ei[e];
        int src = ei[N_EDGES + e];
        unsigned slot = atomicAdd(&cursor[dst], 1u);
        recs[slot] = make_uint2((unsigned)src, __float_as_uint(ew[e]));
    }
}

// ---------------- Phase 4: one wave per node, register accumulation ----------------
__global__ __launch_bounds__(256) void k_gather(const float* __restrict__ X,
                                                const uint2* __restrict__ recs,
                                                const unsigned* __restrict__ base,
                                                float* __restrict__ A) {
    const int node = (blockIdx.x * 256 + threadIdx.x) >> 6;
    const int lane = threadIdx.x & 63;
    if (node >= N_NODES) return;
    const unsigned i0 = base[node], i1 = base[node + 1];
    float acc = 0.f;
    unsigned i = i0;
    for (; i + 8 <= i1; i += 8) {
        uint2 r[8];
        #pragma unroll
        for (int j = 0; j < 8; ++j) r[j] = recs[i + j];
        float v[8];
        #pragma unroll
        for (int j = 0; j < 8; ++j) v[j] = X[(size_t)r[j].x * F_IN + lane];
        #pragma unroll
        for (int j = 0; j < 8; ++j) acc = fmaf(v[j], __uint_as_float(r[j].y), acc);
    }
    for (; i < i1; ++i) {
        uint2 r = recs[i];
        acc = fmaf(X[(size_t)r.x * F_IN + lane], __uint_as_float(r.y), acc);
    }
    A[(size_t)node * F_IN + lane] = acc;
}

// ---------------- Phase 5: projection + bias + ReLU, 8 nodes/block ----------------
__global__ __launch_bounds__(256) void k_proj(const float* __restrict__ A,
                                              const float* __restrict__ W,
                                              const float* __restrict__ bias,
                                              float* __restrict__ out) {
    __shared__ float arows[8 * F_IN];   // 2 KB
    const int t = threadIdx.x;
    const int node0 = blockIdx.x * 8;
    if (t < 128) ((float4*)arows)[t] = ((const float4*)(A + (size_t)node0 * F_IN))[t];
    __syncthreads();

    const int f = t & 127;
    const int g = t >> 7;               // 0..1, each group handles 4 nodes
    float wcol[F_IN];
    #pragma unroll
    for (int k = 0; k < F_IN; ++k) wcol[k] = W[k * F_OUT + f];   // coalesced across f
    const float bf = bias[f];
    for (int n = g * 4; n < g * 4 + 4; ++n) {
        float acc = bf;
        #pragma unroll
        for (int k = 0; k < F_IN; ++k) acc = fmaf(arows[n * F_IN + k], wcol[k], acc);
        out[(size_t)(node0 + n) * F_OUT + f] = fmaxf(acc, 0.0f);
    }
}

// ---- Fused gather+proj (used when workspace can't also hold A) ----
// One block = 4 waves = 4 nodes. Waves accumulate their node's A-row in regs,
// stage to LDS, then all 256 threads project 4 nodes x 128 features (2 each).
__global__ __launch_bounds__(256) void k_gather_proj(const float* __restrict__ X,
                                                     const uint2* __restrict__ recs,
                                                     const unsigned* __restrict__ base,
                                                     const float* __restrict__ W,
                                                     const float* __restrict__ bias,
                                                     float* __restrict__ out) {
    __shared__ float arows[4 * F_IN];   // 1 KB
    const int t = threadIdx.x;
    const int wv = t >> 6, lane = t & 63;
    const int node = blockIdx.x * 4 + wv;

    float acc = 0.f;
    if (node < N_NODES) {
        const unsigned i0 = base[node], i1 = base[node + 1];
        unsigned i = i0;
        for (; i + 8 <= i1; i += 8) {
            uint2 r[8];
            #pragma unroll
            for (int j = 0; j < 8; ++j) r[j] = recs[i + j];
            float v[8];
            #pragma unroll
            for (int j = 0; j < 8; ++j) v[j] = X[(size_t)r[j].x * F_IN + lane];
            #pragma unroll
            for (int j = 0; j < 8; ++j) acc = fmaf(v[j], __uint_as_float(r[j].y), acc);
        }
        for (; i < i1; ++i) {
            uint2 r = recs[i];
            acc = fmaf(X[(size_t)r.x * F_IN + lane], __uint_as_float(r.y), acc);
        }
    }
    arows[wv * F_IN + lane] = acc;
    __syncthreads();

    const int f = t & 127;
    const int g = t >> 7;               // 0..1 -> nodes {g*2, g*2+1}
    const float bf = bias[f];
    for (int n = g * 2; n < g * 2 + 2; ++n) {
        const int nd = blockIdx.x * 4 + n;
        if (nd >= N_NODES) break;
        float acc2 = bf;
        #pragma unroll
        for (int k = 0; k < F_IN; ++k)
            acc2 = fmaf(arows[n * F_IN + k], W[k * F_OUT + f], acc2);
        out[(size_t)nd * F_OUT + f] = fmaxf(acc2, 0.0f);
    }
}

// ---------------- Fallback (round-1 path) if workspace too small ----------------
__global__ __launch_bounds__(256) void gcn_scatter_fb(const float* __restrict__ X,
                                                      const int* __restrict__ ei,
                                                      const float* __restrict__ ew,
                                                      float* __restrict__ A) {
    const int lane = threadIdx.x & 63;
    const int wave = (blockIdx.x * blockDim.x + threadIdx.x) >> 6;
    const int nW = (gridDim.x * blockDim.x) >> 6;
    for (int e = wave; e < N_EDGES; e += nW) {
        const int dst = ei[e];
        const int src = ei[N_EDGES + e];
        atomicAdd(&A[dst * F_IN + lane], X[src * F_IN + lane] * ew[e]);
    }
}
__global__ __launch_bounds__(128) void gcn_proj_fb(const float* __restrict__ A,
                                                   const float* __restrict__ W,
                                                   const float* __restrict__ bias,
                                                   float* __restrict__ out) {
    __shared__ float arow[F_IN];
    const int n = blockIdx.x, f = threadIdx.x;
    if (f < F_IN) arow[f] = A[n * F_IN + f];
    __syncthreads();
    float acc = bias[f];
    #pragma unroll
    for (int k = 0; k < F_IN; ++k) acc = fmaf(arow[k], W[k * F_OUT + f], acc);
    out[n * F_OUT + f] = fmaxf(acc, 0.0f);
}

extern "C" void kernel_launch(void* const* d_in, const int* in_sizes, int n_in,
                              void* d_out, int out_size, void* d_ws, size_t ws_size,
                              hipStream_t stream) {
    const float* X    = (const float*)d_in[0];
    const int*   ei   = (const int*)  d_in[1];
    const float* ew   = (const float*)d_in[2];
    const float* W    = (const float*)d_in[3];
    const float* bias = (const float*)d_in[4];
    float*       out  = (float*)d_out;

    const size_t recs_bytes   = (size_t)N_EDGES * sizeof(uint2);        // 25.6 MB
    const size_t deg_bytes    = (size_t)N_NODES * 4;
    const size_t base_bytes   = (size_t)(N_NODES + 1) * 4;
    const size_t cursor_bytes = (size_t)N_NODES * 4;
    const size_t csum_bytes   = (size_t)((NB_SCAN + 1) * 4);
    const size_t A_bytes      = (size_t)N_NODES * F_IN * sizeof(float); // 25.6 MB
    const size_t need = recs_bytes + deg_bytes + base_bytes + cursor_bytes + csum_bytes;

    if (ws_size >= need) {
        char* p = (char*)d_ws;
        uint2*    recs   = (uint2*)p;                 p += recs_bytes;
        unsigned* deg    = (unsigned*)p;              p += deg_bytes;
        unsigned* base   = (unsigned*)p;              p += base_bytes;
        unsigned* cursor = (unsigned*)p;              p += cursor_bytes;
        unsigned* csum   = (unsigned*)p;              p += csum_bytes;

        hipMemsetAsync(deg, 0, deg_bytes, stream);
        k_hist<<<2048, 256, 0, stream>>>(ei, deg);
        k_scanA<<<NB_SCAN, SCAN_BLK, 0, stream>>>(deg, base, csum);
        k_scanB<<<1, 128, 0, stream>>>(csum, base);
        k_scanC<<<NB_SCAN, SCAN_BLK, 0, stream>>>(csum, base, cursor);
        k_scatter<<<2048, 256, 0, stream>>>(ei, ew, cursor, recs);

        if (ws_size >= need + A_bytes) {
            float* A = (float*)p;
            k_gather<<<(N_NODES + 3) / 4, 256, 0, stream>>>(X, recs, base, A);
            k_proj<<<N_NODES / 8, 256, 0, stream>>>(A, W, bias, out);
        } else {
            k_gather_proj<<<(N_NODES + 3) / 4, 256, 0, stream>>>(X, recs, base, W, bias, out);
        }
    } else {
        float* A = (float*)d_ws;
        hipMemsetAsync(A, 0, A_bytes, stream);
        gcn_scatter_fb<<<4096, 256, 0, stream>>>(X, ei, ew, A);
        gcn_proj_fb<<<N_NODES, 128, 0, stream>>>(A, W, bias, out);
    }
}

// Round 4
// 397.029 us; speedup vs baseline: 4.2877x; 1.3904x over previous
//
#include <hip/hip_runtime.h>

#define N_NODES 100000
#define N_EDGES 3200000
#define F_IN 64
#define F_OUT 128

#define SCAN_BLK 1024
#define NB_SCAN ((N_NODES + SCAN_BLK - 1) / SCAN_BLK)   // 98

#define BSHIFT 8
#define BKT_NODES 256
#define NBKT ((N_NODES + BKT_NODES - 1) / BKT_NODES)    // 391

#define PART_BLOCKS 256
#define PART_THREADS 512
#define CHUNK (N_EDGES / PART_BLOCKS)                    // 12500 exactly

#define SRC_MASK 0x1FFFFu

// ---------------- Phase 1: per-node degree histogram ----------------
__global__ __launch_bounds__(256) void k_hist(const int* __restrict__ ei,
                                              unsigned* __restrict__ deg) {
    int tid = blockIdx.x * 256 + threadIdx.x;
    int stride = gridDim.x * 256;
    for (int e = tid; e < N_EDGES; e += stride) {
        int dst = __builtin_nontemporal_load(&ei[e]);
        atomicAdd(&deg[dst], 1u);
    }
}

// ---------------- Phase 2: exclusive scan over 100K degrees ----------------
__global__ __launch_bounds__(SCAN_BLK) void k_scanA(const unsigned* __restrict__ deg,
                                                    unsigned* __restrict__ base,
                                                    unsigned* __restrict__ csum) {
    __shared__ unsigned s[SCAN_BLK];
    const int t = threadIdx.x;
    const int idx = blockIdx.x * SCAN_BLK + t;
    unsigned v = (idx < N_NODES) ? deg[idx] : 0u;
    s[t] = v;
    __syncthreads();
    for (int off = 1; off < SCAN_BLK; off <<= 1) {
        unsigned u = (t >= off) ? s[t - off] : 0u;
        __syncthreads();
        s[t] += u;
        __syncthreads();
    }
    if (idx < N_NODES) base[idx] = s[t] - v;
    if (t == SCAN_BLK - 1) csum[blockIdx.x] = s[t];
}

__global__ __launch_bounds__(128) void k_scanB(unsigned* __restrict__ csum,
                                               unsigned* __restrict__ base) {
    __shared__ unsigned s[128];
    const int t = threadIdx.x;
    unsigned v = (t < NB_SCAN) ? csum[t] : 0u;
    s[t] = v;
    __syncthreads();
    for (int off = 1; off < 128; off <<= 1) {
        unsigned u = (t >= off) ? s[t - off] : 0u;
        __syncthreads();
        s[t] += u;
        __syncthreads();
    }
    if (t < NB_SCAN) csum[t] = s[t] - v;
    if (t == 0) base[N_NODES] = N_EDGES;
}

// finalize base, init per-node cursor (fallback path) and per-bucket cursor
__global__ __launch_bounds__(SCAN_BLK) void k_scanC(const unsigned* __restrict__ csum,
                                                    unsigned* __restrict__ base,
                                                    unsigned* __restrict__ cursor,
                                                    unsigned* __restrict__ bcur) {
    const int idx = blockIdx.x * SCAN_BLK + threadIdx.x;
    if (idx < N_NODES) {
        unsigned b = base[idx] + csum[blockIdx.x];
        base[idx] = b;
        cursor[idx] = b;
        if ((idx & (BKT_NODES - 1)) == 0) bcur[idx >> BSHIFT] = b;
    }
}

// ---------------- Phase 3a: coarse partition into 391 buckets ----------------
// Block-bulk run reservation: LDS count -> one global atomicAdd per (block,bucket)
// -> records written in contiguous runs of ~25..50 recs (full cache lines).
__global__ __launch_bounds__(PART_THREADS) void k_part(const int* __restrict__ ei,
                                                       const float* __restrict__ ew,
                                                       unsigned* __restrict__ bcur,
                                                       uint2* __restrict__ recs2) {
    __shared__ unsigned cnt[NBKT];
    __shared__ unsigned rbase[NBKT];
    const int t = threadIdx.x;
    const int e0 = blockIdx.x * CHUNK;
    const int e1 = e0 + CHUNK;

    for (int i = t; i < NBKT; i += PART_THREADS) cnt[i] = 0u;
    __syncthreads();
    for (int e = e0 + t; e < e1; e += PART_THREADS) {
        int dst = __builtin_nontemporal_load(&ei[e]);
        atomicAdd(&cnt[dst >> BSHIFT], 1u);
    }
    __syncthreads();
    for (int i = t; i < NBKT; i += PART_THREADS) {
        unsigned c = cnt[i];
        rbase[i] = c ? atomicAdd(&bcur[i], c) : 0u;
        cnt[i] = 0u;
    }
    __syncthreads();
    for (int e = e0 + t; e < e1; e += PART_THREADS) {
        int dst = __builtin_nontemporal_load(&ei[e]);
        int src = __builtin_nontemporal_load(&ei[N_EDGES + e]);
        float w = __builtin_nontemporal_load(&ew[e]);
        int b = dst >> BSHIFT;
        unsigned lo = atomicAdd(&cnt[b], 1u);
        recs2[rbase[b] + lo] =
            make_uint2((unsigned)src | ((unsigned)(dst & (BKT_NODES - 1)) << 17),
                       __float_as_uint(w));
    }
}

// ---------------- Phase 3b: in-bucket reorder to exact per-node slots ----------------
// All writes land inside this bucket's ~64KB region -> lines fill in L2.
__global__ __launch_bounds__(1024) void k_reorder(const uint2* __restrict__ recs2,
                                                  const unsigned* __restrict__ base,
                                                  uint2* __restrict__ recs) {
    __shared__ unsigned lcur[BKT_NODES];
    const int b = blockIdx.x;
    const int t = threadIdx.x;
    const int node0 = b << BSHIFT;
    if (t < BKT_NODES) {
        int n = node0 + t;
        lcur[t] = (n < N_NODES) ? base[n] : 0u;
    }
    __syncthreads();
    const int ncap = (node0 + BKT_NODES <= N_NODES) ? node0 + BKT_NODES : N_NODES;
    const unsigned rbeg = base[node0];
    const unsigned rend = base[ncap];
    for (unsigned i = rbeg + t; i < rend; i += 1024) {
        uint2 r;
        r.x = __builtin_nontemporal_load(&recs2[i].x);
        r.y = __builtin_nontemporal_load(&recs2[i].y);
        unsigned nl = (r.x >> 17) & (BKT_NODES - 1);
        unsigned slot = atomicAdd(&lcur[nl], 1u);
        recs[slot] = r;
    }
}

// ---------------- Phase 4: one wave per node, register accumulation ----------------
__global__ __launch_bounds__(256) void k_gather(const float* __restrict__ X,
                                                const uint2* __restrict__ recs,
                                                const unsigned* __restrict__ base,
                                                float* __restrict__ A) {
    const int node = (blockIdx.x * 256 + threadIdx.x) >> 6;
    const int lane = threadIdx.x & 63;
    if (node >= N_NODES) return;
    const unsigned i0 = base[node], i1 = base[node + 1];
    float acc = 0.f;
    unsigned i = i0;
    for (; i + 8 <= i1; i += 8) {
        uint2 r[8];
        #pragma unroll
        for (int j = 0; j < 8; ++j) r[j] = recs[i + j];
        float v[8];
        #pragma unroll
        for (int j = 0; j < 8; ++j) v[j] = X[(size_t)(r[j].x & SRC_MASK) * F_IN + lane];
        #pragma unroll
        for (int j = 0; j < 8; ++j) acc = fmaf(v[j], __uint_as_float(r[j].y), acc);
    }
    for (; i < i1; ++i) {
        uint2 r = recs[i];
        acc = fmaf(X[(size_t)(r.x & SRC_MASK) * F_IN + lane], __uint_as_float(r.y), acc);
    }
    A[(size_t)node * F_IN + lane] = acc;
}

// ---------------- Phase 5: projection + bias + ReLU, 8 nodes/block ----------------
__global__ __launch_bounds__(256) void k_proj(const float* __restrict__ A,
                                              const float* __restrict__ W,
                                              const float* __restrict__ bias,
                                              float* __restrict__ out) {
    __shared__ float arows[8 * F_IN];
    const int t = threadIdx.x;
    const int node0 = blockIdx.x * 8;
    if (t < 128) ((float4*)arows)[t] = ((const float4*)(A + (size_t)node0 * F_IN))[t];
    __syncthreads();

    const int f = t & 127;
    const int g = t >> 7;
    float wcol[F_IN];
    #pragma unroll
    for (int k = 0; k < F_IN; ++k) wcol[k] = W[k * F_OUT + f];
    const float bf = bias[f];
    for (int n = g * 4; n < g * 4 + 4; ++n) {
        float acc = bf;
        #pragma unroll
        for (int k = 0; k < F_IN; ++k) acc = fmaf(arows[n * F_IN + k], wcol[k], acc);
        out[(size_t)(node0 + n) * F_OUT + f] = fmaxf(acc, 0.0f);
    }
}

// ---- Fused gather+proj (when workspace can't also hold A) ----
__global__ __launch_bounds__(256) void k_gather_proj(const float* __restrict__ X,
                                                     const uint2* __restrict__ recs,
                                                     const unsigned* __restrict__ base,
                                                     const float* __restrict__ W,
                                                     const float* __restrict__ bias,
                                                     float* __restrict__ out) {
    __shared__ float arows[4 * F_IN];
    const int t = threadIdx.x;
    const int wv = t >> 6, lane = t & 63;
    const int node = blockIdx.x * 4 + wv;

    float acc = 0.f;
    if (node < N_NODES) {
        const unsigned i0 = base[node], i1 = base[node + 1];
        unsigned i = i0;
        for (; i + 8 <= i1; i += 8) {
            uint2 r[8];
            #pragma unroll
            for (int j = 0; j < 8; ++j) r[j] = recs[i + j];
            float v[8];
            #pragma unroll
            for (int j = 0; j < 8; ++j) v[j] = X[(size_t)(r[j].x & SRC_MASK) * F_IN + lane];
            #pragma unroll
            for (int j = 0; j < 8; ++j) acc = fmaf(v[j], __uint_as_float(r[j].y), acc);
        }
        for (; i < i1; ++i) {
            uint2 r = recs[i];
            acc = fmaf(X[(size_t)(r.x & SRC_MASK) * F_IN + lane], __uint_as_float(r.y), acc);
        }
    }
    arows[wv * F_IN + lane] = acc;
    __syncthreads();

    const int f = t & 127;
    const int g = t >> 7;
    const float bf = bias[f];
    for (int n = g * 2; n < g * 2 + 2; ++n) {
        const int nd = blockIdx.x * 4 + n;
        if (nd >= N_NODES) break;
        float acc2 = bf;
        #pragma unroll
        for (int k = 0; k < F_IN; ++k)
            acc2 = fmaf(arows[n * F_IN + k], W[k * F_OUT + f], acc2);
        out[(size_t)nd * F_OUT + f] = fmaxf(acc2, 0.0f);
    }
}

// ---- Per-node-cursor scatter (round-3 path, for mid-size workspace) ----
__global__ __launch_bounds__(256) void k_scatter_pn(const int* __restrict__ ei,
                                                    const float* __restrict__ ew,
                                                    unsigned* __restrict__ cursor,
                                                    uint2* __restrict__ recs) {
    int tid = blockIdx.x * 256 + threadIdx.x;
    int stride = gridDim.x * 256;
    for (int e = tid; e < N_EDGES; e += stride) {
        int dst = __builtin_nontemporal_load(&ei[e]);
        int src = __builtin_nontemporal_load(&ei[N_EDGES + e]);
        unsigned slot = atomicAdd(&cursor[dst], 1u);
        recs[slot] = make_uint2((unsigned)src, __float_as_uint(ew[e]));  // no dstLocal; mask-safe
    }
}

// ---------------- Round-1 fallback ----------------
__global__ __launch_bounds__(256) void gcn_scatter_fb(const float* __restrict__ X,
                                                      const int* __restrict__ ei,
                                                      const float* __restrict__ ew,
                                                      float* __restrict__ A) {
    const int lane = threadIdx.x & 63;
    const int wave = (blockIdx.x * blockDim.x + threadIdx.x) >> 6;
    const int nW = (gridDim.x * blockDim.x) >> 6;
    for (int e = wave; e < N_EDGES; e += nW) {
        const int dst = ei[e];
        const int src = ei[N_EDGES + e];
        atomicAdd(&A[dst * F_IN + lane], X[src * F_IN + lane] * ew[e]);
    }
}
__global__ __launch_bounds__(128) void gcn_proj_fb(const float* __restrict__ A,
                                                   const float* __restrict__ W,
                                                   const float* __restrict__ bias,
                                                   float* __restrict__ out) {
    __shared__ float arow[F_IN];
    const int n = blockIdx.x, f = threadIdx.x;
    if (f < F_IN) arow[f] = A[n * F_IN + f];
    __syncthreads();
    float acc = bias[f];
    #pragma unroll
    for (int k = 0; k < F_IN; ++k) acc = fmaf(arow[k], W[k * F_OUT + f], acc);
    out[n * F_OUT + f] = fmaxf(acc, 0.0f);
}

extern "C" void kernel_launch(void* const* d_in, const int* in_sizes, int n_in,
                              void* d_out, int out_size, void* d_ws, size_t ws_size,
                              hipStream_t stream) {
    const float* X    = (const float*)d_in[0];
    const int*   ei   = (const int*)  d_in[1];
    const float* ew   = (const float*)d_in[2];
    const float* W    = (const float*)d_in[3];
    const float* bias = (const float*)d_in[4];
    float*       out  = (float*)d_out;

    const size_t R_bytes    = (size_t)N_EDGES * sizeof(uint2);          // 25.6 MB
    const size_t A_bytes    = (size_t)N_NODES * F_IN * sizeof(float);   // 25.6 MB
    const size_t deg_bytes  = (size_t)N_NODES * 4;
    const size_t base_bytes = (size_t)(N_NODES + 1) * 4;
    const size_t cur_bytes  = (size_t)N_NODES * 4;
    const size_t csum_bytes = (size_t)(NB_SCAN + 1) * 4;
    const size_t bcur_bytes = (size_t)NBKT * 4;
    const size_t meta_bytes = deg_bytes + base_bytes + cur_bytes + csum_bytes + bcur_bytes;

    const size_t need1 = 2 * R_bytes + A_bytes + meta_bytes;  // full pipeline
    const size_t need2 = 2 * R_bytes + meta_bytes;            // fused proj
    const size_t need4 = R_bytes + meta_bytes;                // round-3 style
    const size_t need5 = A_bytes;                             // round-1 atomics

    if (ws_size >= need2) {
        char* p = (char*)d_ws;
        uint2*    recs2  = (uint2*)p;       p += R_bytes;
        uint2*    recs   = (uint2*)p;       p += R_bytes;
        float*    A      = nullptr;
        if (ws_size >= need1) { A = (float*)p; p += A_bytes; }
        unsigned* deg    = (unsigned*)p;    p += deg_bytes;
        unsigned* base   = (unsigned*)p;    p += base_bytes;
        unsigned* cursor = (unsigned*)p;    p += cur_bytes;
        unsigned* csum   = (unsigned*)p;    p += csum_bytes;
        unsigned* bcur   = (unsigned*)p;    p += bcur_bytes;

        hipMemsetAsync(deg, 0, deg_bytes, stream);
        k_hist<<<2048, 256, 0, stream>>>(ei, deg);
        k_scanA<<<NB_SCAN, SCAN_BLK, 0, stream>>>(deg, base, csum);
        k_scanB<<<1, 128, 0, stream>>>(csum, base);
        k_scanC<<<NB_SCAN, SCAN_BLK, 0, stream>>>(csum, base, cursor, bcur);
        k_part<<<PART_BLOCKS, PART_THREADS, 0, stream>>>(ei, ew, bcur, recs2);
        k_reorder<<<NBKT, 1024, 0, stream>>>(recs2, base, recs);

        if (A) {
            k_gather<<<(N_NODES + 3) / 4, 256, 0, stream>>>(X, recs, base, A);
            k_proj<<<N_NODES / 8, 256, 0, stream>>>(A, W, bias, out);
        } else {
            k_gather_proj<<<(N_NODES + 3) / 4, 256, 0, stream>>>(X, recs, base, W, bias, out);
        }
    } else if (ws_size >= need4) {
        char* p = (char*)d_ws;
        uint2*    recs   = (uint2*)p;       p += R_bytes;
        unsigned* deg    = (unsigned*)p;    p += deg_bytes;
        unsigned* base   = (unsigned*)p;    p += base_bytes;
        unsigned* cursor = (unsigned*)p;    p += cur_bytes;
        unsigned* csum   = (unsigned*)p;    p += csum_bytes;
        unsigned* bcur   = (unsigned*)p;    p += bcur_bytes;

        hipMemsetAsync(deg, 0, deg_bytes, stream);
        k_hist<<<2048, 256, 0, stream>>>(ei, deg);
        k_scanA<<<NB_SCAN, SCAN_BLK, 0, stream>>>(deg, base, csum);
        k_scanB<<<1, 128, 0, stream>>>(csum, base);
        k_scanC<<<NB_SCAN, SCAN_BLK, 0, stream>>>(csum, base, cursor, bcur);
        k_scatter_pn<<<2048, 256, 0, stream>>>(ei, ew, cursor, recs);
        k_gather_proj<<<(N_NODES + 3) / 4, 256, 0, stream>>>(X, recs, base, W, bias, out);
    } else if (ws_size >= need5) {
        float* A = (float*)d_ws;
        hipMemsetAsync(A, 0, A_bytes, stream);
        gcn_scatter_fb<<<4096, 256, 0, stream>>>(X, ei, ew, A);
        gcn_proj_fb<<<N_NODES, 128, 0, stream>>>(A, W, bias, out);
    }
}

// Round 5
// 346.735 us; speedup vs baseline: 4.9096x; 1.1450x over previous
//
#include <hip/hip_runtime.h>

#define N_NODES 100000
#define N_EDGES 3200000
#define F_IN 64
#define F_OUT 128

#define BSHIFT 7
#define BKT_NODES 128                                   // nodes per bucket
#define NBKT ((N_NODES + BKT_NODES - 1) / BKT_NODES)    // 782
#define CAP2 4736                                       // bucket capacity (mean 4096 + 10 sigma)

#define PART_BLOCKS 256
#define PART_THREADS 1024
#define CHUNK (N_EDGES / PART_BLOCKS)                   // 12500 exactly

#define SRC_MASK 0x1FFFFu

// ---------------- Phase 1: partition edges into 782 fixed-capacity buckets ----
// Block-bulk run reservation: LDS count -> one global atomicAdd per (block,bucket)
// -> contiguous runs of ~16 records. dst chunk cached in LDS (read once).
__global__ __launch_bounds__(PART_THREADS) void k_part(const int* __restrict__ ei,
                                                       const float* __restrict__ ew,
                                                       unsigned* __restrict__ bcur,
                                                       uint2* __restrict__ recs2) {
    __shared__ unsigned cnt[NBKT];
    __shared__ unsigned rbase[NBKT];
    __shared__ int sdst[CHUNK];                          // 50 KB
    const int t = threadIdx.x;
    const int e0 = blockIdx.x * CHUNK;

    for (int i = t; i < NBKT; i += PART_THREADS) cnt[i] = 0u;
    __syncthreads();
    for (int k = t; k < CHUNK; k += PART_THREADS) {
        int dst = __builtin_nontemporal_load(&ei[e0 + k]);
        sdst[k] = dst;
        atomicAdd(&cnt[dst >> BSHIFT], 1u);
    }
    __syncthreads();
    for (int i = t; i < NBKT; i += PART_THREADS) {
        unsigned c = cnt[i];
        rbase[i] = c ? atomicAdd(&bcur[i], c) : 0u;
        cnt[i] = 0u;
    }
    __syncthreads();
    for (int k = t; k < CHUNK; k += PART_THREADS) {
        int dst = sdst[k];
        int src = __builtin_nontemporal_load(&ei[N_EDGES + e0 + k]);
        float w = __builtin_nontemporal_load(&ew[e0 + k]);
        int b = dst >> BSHIFT;
        unsigned lo = atomicAdd(&cnt[b], 1u);
        recs2[(size_t)b * CAP2 + rbase[b] + lo] =
            make_uint2((unsigned)src | ((unsigned)(dst & (BKT_NODES - 1)) << 17),
                       __float_as_uint(w));
    }
}

// ---------------- Phase 2: fused in-LDS sort + gather + projection ------------
// One block per bucket: count/scan/place records in LDS, per-wave-per-node
// register gather from X, stage A-rows in reused LDS, proj+bias+ReLU to out.
__global__ __launch_bounds__(512) void k_fused(const float* __restrict__ X,
                                               const uint2* __restrict__ recs2,
                                               const unsigned* __restrict__ bcnt,
                                               const float* __restrict__ W,
                                               const float* __restrict__ bias,
                                               float* __restrict__ out) {
    __shared__ __align__(16) union {
        uint2 srec[CAP2];                 // 37.9 KB (sort phase)
        float arows[BKT_NODES * F_IN];    // 32 KB   (proj phase)
    } u;
    __shared__ unsigned lcnt[BKT_NODES];
    __shared__ unsigned sincl[BKT_NODES];
    __shared__ unsigned lcur[BKT_NODES];

    const int t = threadIdx.x;
    const int b = blockIdx.x;
    const int node0 = b << BSHIFT;
    const int nNodes = (N_NODES - node0 < BKT_NODES) ? (N_NODES - node0) : BKT_NODES;
    const unsigned cnt = bcnt[b];
    const uint2* run = recs2 + (size_t)b * CAP2;

    if (t < BKT_NODES) { lcnt[t] = 0u; lcur[t] = 0u; }
    __syncthreads();

    // pass A: count records per local node
    for (unsigned i = t; i < cnt; i += 512) {
        unsigned x = run[i].x;
        atomicAdd(&lcnt[(x >> 17) & (BKT_NODES - 1)], 1u);
    }
    __syncthreads();

    // inclusive Hillis-Steele scan over 128 counters (all threads hit barriers)
    if (t < BKT_NODES) sincl[t] = lcnt[t];
    __syncthreads();
    for (int off = 1; off < BKT_NODES; off <<= 1) {
        unsigned uu = (t < BKT_NODES && t >= off) ? sincl[t - off] : 0u;
        __syncthreads();
        if (t < BKT_NODES) sincl[t] += uu;
        __syncthreads();
    }

    // pass B: place records node-sorted into LDS
    for (unsigned i = t; i < cnt; i += 512) {
        uint2 r = run[i];
        unsigned nl = (r.x >> 17) & (BKT_NODES - 1);
        unsigned slot = sincl[nl] - lcnt[nl] + atomicAdd(&lcur[nl], 1u);
        u.srec[slot] = r;
    }
    __syncthreads();

    // gather: 8 waves x 16 nodes each; lane = input feature; acc in registers
    const int wv = t >> 6;
    const int lane = t & 63;
    float accs[16];
    #pragma unroll
    for (int j = 0; j < 16; ++j) {
        const int n = wv * 16 + j;
        const unsigned i1 = sincl[n];
        unsigned i = i1 - lcnt[n];
        float acc = 0.f;
        for (; i + 8 <= i1; i += 8) {
            uint2 r[8];
            #pragma unroll
            for (int q = 0; q < 8; ++q) r[q] = u.srec[i + q];      // LDS broadcast
            float v[8];
            #pragma unroll
            for (int q = 0; q < 8; ++q) v[q] = X[(size_t)(r[q].x & SRC_MASK) * F_IN + lane];
            #pragma unroll
            for (int q = 0; q < 8; ++q) acc = fmaf(v[q], __uint_as_float(r[q].y), acc);
        }
        for (; i < i1; ++i) {
            uint2 r = u.srec[i];
            acc = fmaf(X[(size_t)(r.x & SRC_MASK) * F_IN + lane], __uint_as_float(r.y), acc);
        }
        accs[j] = acc;
    }
    __syncthreads();                       // all srec reads complete

    #pragma unroll
    for (int j = 0; j < 16; ++j)
        u.arows[(wv * 16 + j) * F_IN + lane] = accs[j];
    __syncthreads();

    // proj: f = output feature, 4 groups interleave over nodes.
    // arows reads are wave-broadcast; W is L1-resident (32 KB).
    const int f = t & 127;
    const int g = t >> 7;
    const float bf = bias[f];
    for (int n = g; n < nNodes; n += 4) {
        float acc = bf;
        #pragma unroll
        for (int k4 = 0; k4 < F_IN / 4; ++k4) {
            float4 a4 = *(const float4*)&u.arows[n * F_IN + k4 * 4];
            acc = fmaf(a4.x, W[(k4 * 4 + 0) * F_OUT + f], acc);
            acc = fmaf(a4.y, W[(k4 * 4 + 1) * F_OUT + f], acc);
            acc = fmaf(a4.z, W[(k4 * 4 + 2) * F_OUT + f], acc);
            acc = fmaf(a4.w, W[(k4 * 4 + 3) * F_OUT + f], acc);
        }
        out[(size_t)(node0 + n) * F_OUT + f] = fmaxf(acc, 0.f);
    }
}

// ---------------- Fallback (round-1 path) if workspace too small --------------
__global__ __launch_bounds__(256) void gcn_scatter_fb(const float* __restrict__ X,
                                                      const int* __restrict__ ei,
                                                      const float* __restrict__ ew,
                                                      float* __restrict__ A) {
    const int lane = threadIdx.x & 63;
    const int wave = (blockIdx.x * blockDim.x + threadIdx.x) >> 6;
    const int nW = (gridDim.x * blockDim.x) >> 6;
    for (int e = wave; e < N_EDGES; e += nW) {
        const int dst = ei[e];
        const int src = ei[N_EDGES + e];
        atomicAdd(&A[dst * F_IN + lane], X[src * F_IN + lane] * ew[e]);
    }
}
__global__ __launch_bounds__(128) void gcn_proj_fb(const float* __restrict__ A,
                                                   const float* __restrict__ W,
                                                   const float* __restrict__ bias,
                                                   float* __restrict__ out) {
    __shared__ float arow[F_IN];
    const int n = blockIdx.x, f = threadIdx.x;
    if (f < F_IN) arow[f] = A[n * F_IN + f];
    __syncthreads();
    float acc = bias[f];
    #pragma unroll
    for (int k = 0; k < F_IN; ++k) acc = fmaf(arow[k], W[k * F_OUT + f], acc);
    out[n * F_OUT + f] = fmaxf(acc, 0.0f);
}

extern "C" void kernel_launch(void* const* d_in, const int* in_sizes, int n_in,
                              void* d_out, int out_size, void* d_ws, size_t ws_size,
                              hipStream_t stream) {
    const float* X    = (const float*)d_in[0];
    const int*   ei   = (const int*)  d_in[1];
    const float* ew   = (const float*)d_in[2];
    const float* W    = (const float*)d_in[3];
    const float* bias = (const float*)d_in[4];
    float*       out  = (float*)d_out;

    const size_t recs2_bytes = (size_t)NBKT * CAP2 * sizeof(uint2);   // 29.6 MB
    const size_t bcnt_bytes  = (size_t)NBKT * sizeof(unsigned);

    if (ws_size >= recs2_bytes + bcnt_bytes) {
        uint2*    recs2 = (uint2*)d_ws;
        unsigned* bcur  = (unsigned*)((char*)d_ws + recs2_bytes);

        hipMemsetAsync(bcur, 0, bcnt_bytes, stream);
        k_part<<<PART_BLOCKS, PART_THREADS, 0, stream>>>(ei, ew, bcur, recs2);
        k_fused<<<NBKT, 512, 0, stream>>>(X, recs2, bcur, W, bias, out);
    } else {
        float* A = (float*)d_ws;   // 25.6 MB
        hipMemsetAsync(A, 0, (size_t)N_NODES * F_IN * sizeof(float), stream);
        gcn_scatter_fb<<<4096, 256, 0, stream>>>(X, ei, ew, A);
        gcn_proj_fb<<<N_NODES, 128, 0, stream>>>(A, W, bias, out);
    }
}